// Round 14
// baseline (39.346 us; speedup 1.0000x reference)
//
#include <hip/hip_runtime.h>
#include <math.h>

#define HW 256
#define TW 64
#define TH 32
#define LW 68           // 2 halo + 64 + 2 halo (272B row stride, 16B-aligned)
#define LH 36           // 2 halo + 32 + 2 halo

// Schraudolph exp2: 2^x ~= bits(u32((x + 127 - sigma) * 2^23)), x <= 0.
// Error cancels in softmax normalization (R7/R11: absmax identical to exact).
#define EXP2_C23 8388608.0f                 // 2^23
#define EXP2_B   1065056256.0f              // (127 - 0.0354) * 2^23

typedef float f32x2 __attribute__((ext_vector_type(2)));

__device__ __forceinline__ int reflect_idx(int i) {
    i = (i < 0) ? -i : i;
    i = (i >= HW) ? (2 * HW - 2 - i) : i;
    return i;
}

__device__ __forceinline__ float4 max4(float4 a, float4 b) {
    float4 r; r.x = fmaxf(a.x, b.x); r.y = fmaxf(a.y, b.y);
    r.z = fmaxf(a.z, b.z); r.w = fmaxf(a.w, b.w); return r;
}
__device__ __forceinline__ float4 max34(float4 a, float4 b, float4 c) {
    float4 r; r.x = fmaxf(fmaxf(a.x, b.x), c.x); r.y = fmaxf(fmaxf(a.y, b.y), c.y);
    r.z = fmaxf(fmaxf(a.z, b.z), c.z); r.w = fmaxf(fmaxf(a.w, b.w), c.w); return r;
}
__device__ __forceinline__ float4 add4(float4 a, float4 b) {
    float4 r; r.x = a.x + b.x; r.y = a.y + b.y;
    r.z = a.z + b.z; r.w = a.w + b.w; return r;
}
__device__ __forceinline__ float4 sub4(float4 a, float4 b) {
    float4 r; r.x = a.x - b.x; r.y = a.y - b.y;
    r.z = a.z - b.z; r.w = a.w - b.w; return r;
}

// One output row, 4 pixels, packed f32x2 tap loop.
// USE_TRANS=1: v_exp_f32 (trans pipe). USE_TRANS=0: Schraudolph (VALU pipe).
template <int USE_TRANS>
__device__ __forceinline__ void proc_row(
    float4 A0, float4 B0, float4 A1, float4 B1, float4 A2, float4 B2,
    float4 A3, float4 B3, float4 A4, float4 B4,
    float4 cmA, float4 cmB, float4 csA, float4 csB,
    float bp, float c04b, float inv_bp, float lam,
    float* __restrict__ orow)
{
    const float cs[8] = {csA.x,csA.y,csA.z,csA.w, csB.x,csB.y,csB.z,csB.w};
    const float cm[8] = {cmA.x,cmA.y,cmA.z,cmA.w, cmB.x,cmB.y,cmB.z,cmB.w};
    const float vv[5][8] = {
        {A0.x,A0.y,A0.z,A0.w, B0.x,B0.y,B0.z,B0.w},
        {A1.x,A1.y,A1.z,A1.w, B1.x,B1.y,B1.z,B1.w},
        {A2.x,A2.y,A2.z,A2.w, B2.x,B2.y,B2.z,B2.w},
        {A3.x,A3.y,A3.z,A3.w, B3.x,B3.y,B3.z,B3.w},
        {A4.x,A4.y,A4.z,A4.w, B4.x,B4.y,B4.z,B4.w}};

    // Sliding horizontal sums of the 8 column sums (5-wide windows)
    const float t12 = cs[1] + cs[2];
    const float t34 = cs[3] + cs[4];
    const float t56 = cs[5] + cs[6];
    const float u   = t12 + t34;
    const float w_  = t34 + t56;
    const float S[4] = {cs[0] + u, u + cs[5], cs[2] + w_, w_ + cs[7]};

    // Horizontal max of 5 column-maxes with shared pairs (v_max3 fusion)
    const float h12 = fmaxf(cm[1], cm[2]);
    const float h34 = fmaxf(cm[3], cm[4]);
    const float h56 = fmaxf(cm[5], cm[6]);
    const float m[4] = {fmaxf(fmaxf(cm[0], h12), h34),
                        fmaxf(fmaxf(h12, h34), cm[5]),
                        fmaxf(fmaxf(cm[2], h34), h56),
                        fmaxf(fmaxf(h34, h56), cm[7])};

    const f32x2 bp2   = {bp, bp};
    const f32x2 nbm01 = {-(S[0] * c04b), -(S[1] * c04b)};
    const f32x2 nbm23 = {-(S[2] * c04b), -(S[3] * c04b)};
    f32x2 ws01 = {0.0f, 0.0f}, ws23 = {0.0f, 0.0f};
    f32x2 wa01 = {0.0f, 0.0f}, wa23 = {0.0f, 0.0f};

    #pragma unroll
    for (int k = 0; k < 5; ++k) {
        #pragma unroll
        for (int j = 0; j < 5; ++j) {
            const f32x2 v01 = {vv[k][j],     vv[k][j + 1]};
            const f32x2 v23 = {vv[k][j + 2], vv[k][j + 3]};
            const f32x2 tv01 = __builtin_elementwise_fma(bp2, v01, nbm01);
            const f32x2 tv23 = __builtin_elementwise_fma(bp2, v23, nbm23);
            f32x2 e01, e23;
            if (USE_TRANS) {
                e01.x = __builtin_amdgcn_exp2f(-fabsf(tv01.x));
                e01.y = __builtin_amdgcn_exp2f(-fabsf(tv01.y));
                e23.x = __builtin_amdgcn_exp2f(-fabsf(tv23.x));
                e23.y = __builtin_amdgcn_exp2f(-fabsf(tv23.y));
            } else {
                e01.x = __uint_as_float(__float2uint_rz(fmaf(-fabsf(tv01.x), EXP2_C23, EXP2_B)));
                e01.y = __uint_as_float(__float2uint_rz(fmaf(-fabsf(tv01.y), EXP2_C23, EXP2_B)));
                e23.x = __uint_as_float(__float2uint_rz(fmaf(-fabsf(tv23.x), EXP2_C23, EXP2_B)));
                e23.y = __uint_as_float(__float2uint_rz(fmaf(-fabsf(tv23.y), EXP2_C23, EXP2_B)));
            }
            ws01 += e01;                                        // v_pk_add_f32
            ws23 += e23;
            wa01 = __builtin_elementwise_fma(e01, tv01, wa01);  // v_pk_fma_f32
            wa23 = __builtin_elementwise_fma(e23, tv23, wa23);
        }
    }

    const float ws[4] = {ws01.x, ws01.y, ws23.x, ws23.y};
    const float wa[4] = {wa01.x, wa01.y, wa23.x, wa23.y};

    float o[4];
    #pragma unroll
    for (int p = 0; p < 4; ++p) {
        const float mean = S[p] * 0.04f;
        const float med  = fmaf(wa[p] * __builtin_amdgcn_rcpf(ws[p]), inv_bp, mean);
        o[p] = fmaf(lam, med - m[p], m[p]);
    }
    float4 o4; o4.x = o[0]; o4.y = o[1]; o4.z = o[2]; o4.w = o[3];
    *(float4*)orow = o4;
}

__global__ __launch_bounds__(256, 4)
void maxmedian_kernel(const float* __restrict__ x,
                      const float* __restrict__ mix,
                      const float* __restrict__ beta_raw,
                      float* __restrict__ out,
                      int C) {
    __shared__ __align__(16) float tile[LH * LW];

    const int tiles_x = HW / TW;                       // 4
    const int tiles_per_plane = tiles_x * (HW / TH);   // 32
    const int plane = blockIdx.x / tiles_per_plane;
    const int t     = blockIdx.x % tiles_per_plane;
    const int ty0 = (t / tiles_x) * TH;
    const int tx0 = (t % tiles_x) * TW;

    const float* __restrict__ xp = x + (size_t)plane * (HW * HW);
    const int tid = threadIdx.x;

    // ---- Stage (TH+4) x (TW+4) with reflect padding ----
    {
        const int c   = tid & 63;
        const int r0s = tid >> 6;             // 0..3
        const int gx  = tx0 + c;
        #pragma unroll
        for (int k = 0; k < 9; ++k) {
            const int r  = r0s + 4 * k;       // 0..35
            const int gy = reflect_idx(ty0 + r - 2);
            tile[r * LW + c + 2] = xp[gy * HW + gx];
        }
        if (tid < 144) {                      // cols {0,1,66,67} x 36 rows
            const int jj = tid & 3;
            const int j  = (jj < 2) ? jj : (64 + jj);
            const int r  = tid >> 2;
            const int gx2 = reflect_idx(tx0 + j - 2);
            const int gy2 = reflect_idx(ty0 + r - 2);
            tile[r * LW + j] = xp[gy2 * HW + gx2];
        }
    }
    __syncthreads();

    // ---- Parameters ----
    const int ch = plane % C;
    const float lam  = 1.0f / (1.0f + __expf(-mix[ch]));
    const float beta = 5.0f + 45.0f / (1.0f + __expf(-beta_raw[0]));
    const float bp     = beta * 1.44269504088896f;   // beta * log2(e) > 0
    const float inv_bp = 1.0f / bp;
    const float c04b   = 0.04f * bp;

    // ---- Each thread: 4-wide x 2-tall ----
    const int tx  = tid & 15;
    const int ryq = tid >> 4;        // 0..15
    const int r0  = ryq * 2;
    const float* lbase = &tile[r0 * LW + 4 * tx];

    float4 w0a = *(const float4*)(lbase + 0 * LW);
    float4 w0b = *(const float4*)(lbase + 0 * LW + 4);
    float4 w1a = *(const float4*)(lbase + 1 * LW);
    float4 w1b = *(const float4*)(lbase + 1 * LW + 4);
    float4 w2a = *(const float4*)(lbase + 2 * LW);
    float4 w2b = *(const float4*)(lbase + 2 * LW + 4);
    float4 w3a = *(const float4*)(lbase + 3 * LW);
    float4 w3b = *(const float4*)(lbase + 3 * LW + 4);
    float4 w4a = *(const float4*)(lbase + 4 * LW);
    float4 w4b = *(const float4*)(lbase + 4 * LW + 4);
    float4 w5a = *(const float4*)(lbase + 5 * LW);
    float4 w5b = *(const float4*)(lbase + 5 * LW + 4);

    float4 csA = add4(add4(add4(w0a, w1a), add4(w2a, w3a)), w4a);
    float4 csB = add4(add4(add4(w0b, w1b), add4(w2b, w3b)), w4b);

    const float4 p12a = max4(w1a, w2a), p12b = max4(w1b, w2b);
    const float4 p34a = max4(w3a, w4a), p34b = max4(w3b, w4b);
    const float4 cm0a = max34(w0a, p12a, p34a);
    const float4 cm0b = max34(w0b, p12b, p34b);

    float* __restrict__ orow =
        out + (size_t)plane * (HW * HW) + (size_t)(ty0 + r0) * HW + (tx0 + 4 * tx);

    // Row 0: trans-pipe exp. Row 1: VALU Schraudolph. Halves trans-pipe load.
    proc_row<1>(w0a,w0b, w1a,w1b, w2a,w2b, w3a,w3b, w4a,w4b,
                cm0a, cm0b, csA, csB, bp, c04b, inv_bp, lam, orow);

    csA = add4(csA, sub4(w5a, w0a));
    csB = add4(csB, sub4(w5b, w0b));
    const float4 cm1a = max34(p12a, p34a, w5a);
    const float4 cm1b = max34(p12b, p34b, w5b);

    proc_row<0>(w1a,w1b, w2a,w2b, w3a,w3b, w4a,w4b, w5a,w5b,
                cm1a, cm1b, csA, csB, bp, c04b, inv_bp, lam, orow + HW);
}

extern "C" void kernel_launch(void* const* d_in, const int* in_sizes, int n_in,
                              void* d_out, int out_size, void* d_ws, size_t ws_size,
                              hipStream_t stream) {
    const float* x        = (const float*)d_in[0];
    const float* mix      = (const float*)d_in[1];
    const float* beta_raw = (const float*)d_in[2];
    float* out            = (float*)d_out;

    const int planes = in_sizes[0] / (HW * HW);                 // 128
    const int C      = in_sizes[1];                             // 32
    const int tiles_per_plane = (HW / TW) * (HW / TH);          // 32
    const int grid = planes * tiles_per_plane;                  // 4096

    maxmedian_kernel<<<grid, 256, 0, stream>>>(x, mix, beta_raw, out, C);
}

// Round 15
// 37.616 us; speedup vs baseline: 1.0460x; 1.0460x over previous
//
#include <hip/hip_runtime.h>
#include <math.h>

#define HW 256
#define LW 68           // 2 halo + 64 + 2 halo
#define WLH 12          // per-wave tile rows: 8 output + 4 halo
#define NT 4            // horizontal tiles per band

typedef float f32x2 __attribute__((ext_vector_type(2)));

__device__ __forceinline__ int reflect_idx(int i) {
    i = (i < 0) ? -i : i;
    i = (i >= HW) ? (2 * HW - 2 - i) : i;
    return i;
}

__device__ __forceinline__ float4 max4(float4 a, float4 b) {
    float4 r; r.x = fmaxf(a.x, b.x); r.y = fmaxf(a.y, b.y);
    r.z = fmaxf(a.z, b.z); r.w = fmaxf(a.w, b.w); return r;
}
__device__ __forceinline__ float4 max34(float4 a, float4 b, float4 c) {
    float4 r; r.x = fmaxf(fmaxf(a.x, b.x), c.x); r.y = fmaxf(fmaxf(a.y, b.y), c.y);
    r.z = fmaxf(fmaxf(a.z, b.z), c.z); r.w = fmaxf(fmaxf(a.w, b.w), c.w); return r;
}
__device__ __forceinline__ float4 add4(float4 a, float4 b) {
    float4 r; r.x = a.x + b.x; r.y = a.y + b.y;
    r.z = a.z + b.z; r.w = a.w + b.w; return r;
}
__device__ __forceinline__ float4 sub4(float4 a, float4 b) {
    float4 r; r.x = a.x - b.x; r.y = a.y - b.y;
    r.z = a.z - b.z; r.w = a.w - b.w; return r;
}

struct Stage {          // one tile's staged data held in registers (13 VGPRs)
    float m[WLH];
    float h;
};

// One output row, 4 pixels, packed f32x2 tap loop with trans-pipe exp (R13).
__device__ __forceinline__ void proc_row(
    float4 A0, float4 B0, float4 A1, float4 B1, float4 A2, float4 B2,
    float4 A3, float4 B3, float4 A4, float4 B4,
    float4 cmA, float4 cmB, float4 csA, float4 csB,
    float bp, float c04b, float inv_bp, float lam,
    float* __restrict__ orow)
{
    const float cs[8] = {csA.x,csA.y,csA.z,csA.w, csB.x,csB.y,csB.z,csB.w};
    const float cm[8] = {cmA.x,cmA.y,cmA.z,cmA.w, cmB.x,cmB.y,cmB.z,cmB.w};
    const float vv[5][8] = {
        {A0.x,A0.y,A0.z,A0.w, B0.x,B0.y,B0.z,B0.w},
        {A1.x,A1.y,A1.z,A1.w, B1.x,B1.y,B1.z,B1.w},
        {A2.x,A2.y,A2.z,A2.w, B2.x,B2.y,B2.z,B2.w},
        {A3.x,A3.y,A3.z,A3.w, B3.x,B3.y,B3.z,B3.w},
        {A4.x,A4.y,A4.z,A4.w, B4.x,B4.y,B4.z,B4.w}};

    const float t12 = cs[1] + cs[2];
    const float t34 = cs[3] + cs[4];
    const float t56 = cs[5] + cs[6];
    const float u   = t12 + t34;
    const float w_  = t34 + t56;
    const float S[4] = {cs[0] + u, u + cs[5], cs[2] + w_, w_ + cs[7]};

    const float h12 = fmaxf(cm[1], cm[2]);
    const float h34 = fmaxf(cm[3], cm[4]);
    const float h56 = fmaxf(cm[5], cm[6]);
    const float m[4] = {fmaxf(fmaxf(cm[0], h12), h34),
                        fmaxf(fmaxf(h12, h34), cm[5]),
                        fmaxf(fmaxf(cm[2], h34), h56),
                        fmaxf(fmaxf(h34, h56), cm[7])};

    const f32x2 bp2   = {bp, bp};
    const f32x2 nbm01 = {-(S[0] * c04b), -(S[1] * c04b)};
    const f32x2 nbm23 = {-(S[2] * c04b), -(S[3] * c04b)};
    f32x2 ws01 = {0.0f, 0.0f}, ws23 = {0.0f, 0.0f};
    f32x2 wa01 = {0.0f, 0.0f}, wa23 = {0.0f, 0.0f};

    #pragma unroll
    for (int k = 0; k < 5; ++k) {
        #pragma unroll
        for (int j = 0; j < 5; ++j) {
            const f32x2 v01 = {vv[k][j],     vv[k][j + 1]};
            const f32x2 v23 = {vv[k][j + 2], vv[k][j + 3]};
            const f32x2 tv01 = __builtin_elementwise_fma(bp2, v01, nbm01);
            const f32x2 tv23 = __builtin_elementwise_fma(bp2, v23, nbm23);
            f32x2 e01, e23;
            e01.x = __builtin_amdgcn_exp2f(-fabsf(tv01.x));
            e01.y = __builtin_amdgcn_exp2f(-fabsf(tv01.y));
            e23.x = __builtin_amdgcn_exp2f(-fabsf(tv23.x));
            e23.y = __builtin_amdgcn_exp2f(-fabsf(tv23.y));
            ws01 += e01;
            ws23 += e23;
            wa01 = __builtin_elementwise_fma(e01, tv01, wa01);
            wa23 = __builtin_elementwise_fma(e23, tv23, wa23);
        }
    }

    const float ws[4] = {ws01.x, ws01.y, ws23.x, ws23.y};
    const float wa[4] = {wa01.x, wa01.y, wa23.x, wa23.y};

    float o[4];
    #pragma unroll
    for (int p = 0; p < 4; ++p) {
        const float mean = S[p] * 0.04f;
        const float med  = fmaf(wa[p] * __builtin_amdgcn_rcpf(ws[p]), inv_bp, mean);
        o[p] = fmaf(lam, med - m[p], m[p]);
    }
    float4 o4; o4.x = o[0]; o4.y = o[1]; o4.z = o[2]; o4.w = o[3];
    *(float4*)orow = o4;
}

__global__ __launch_bounds__(256)
void maxmedian_kernel(const float* __restrict__ x,
                      const float* __restrict__ mix,
                      const float* __restrict__ beta_raw,
                      float* __restrict__ out,
                      int C) {
    // Per-wave double-buffered tiles: 4 waves x 2 bufs x 12 x 68 (25.5 KB).
    __shared__ __align__(16) float lds[4][2][WLH * LW];

    const int tid  = threadIdx.x;
    const int wave = tid >> 6;
    const int lane = tid & 63;

    // Each wave owns one 8-row x 256-col band, processed as 4 tiles of 64.
    const int band  = blockIdx.x * 4 + wave;   // 0..4095
    const int plane = band >> 5;               // 32 bands per plane
    const int by0   = (band & 31) << 3;        // band's first output row

    const float* __restrict__ xp = x + (size_t)plane * (HW * HW);

    // Row addresses (vertical reflect), constant across the band's tiles.
    int gy[WLH];
    #pragma unroll
    for (int k = 0; k < WLH; ++k) gy[k] = reflect_idx(by0 - 2 + k) * HW;

    // Halo-lane mapping (lanes 0..47): 4 cols x 12 rows.
    const int hj   = lane & 3;
    const int hcol = (hj < 2) ? hj : (64 + hj);        // LDS col 0,1,66,67
    const int hoff = hcol - 2;                         // -2,-1,64,65
    const int gyh  = reflect_idx(by0 - 2 + (lane >> 2)) * HW;

    // ---- Parameters ----
    const int ch = plane % C;
    const float lam  = 1.0f / (1.0f + __expf(-mix[ch]));
    const float beta = 5.0f + 45.0f / (1.0f + __expf(-beta_raw[0]));
    const float bp     = beta * 1.44269504088896f;
    const float inv_bp = 1.0f / bp;
    const float c04b   = 0.04f * bp;

    // Compute-lane mapping (wave-local): 4 cols x 2 rows per lane.
    const int tx = lane & 15;
    const int r0 = (lane >> 4) * 2;

    // ---- helpers as lambdas (static indices everywhere) ----
    auto stage_load = [&](int t, Stage& s) {
        const int c0 = t * 64;
        #pragma unroll
        for (int k = 0; k < WLH; ++k)
            s.m[k] = xp[gy[k] + c0 + lane];
        if (lane < 48)
            s.h = xp[gyh + reflect_idx(c0 + hoff)];
    };
    auto stage_write = [&](int buf, const Stage& s) {
        float* __restrict__ b = lds[wave][buf];
        #pragma unroll
        for (int k = 0; k < WLH; ++k)
            b[k * LW + 2 + lane] = s.m[k];
        if (lane < 48)
            b[(lane >> 2) * LW + hcol] = s.h;
    };
    auto compute = [&](int t, int buf) {
        const float* lbase = &lds[wave][buf][r0 * LW + 4 * tx];

        float4 w0a = *(const float4*)(lbase + 0 * LW);
        float4 w0b = *(const float4*)(lbase + 0 * LW + 4);
        float4 w1a = *(const float4*)(lbase + 1 * LW);
        float4 w1b = *(const float4*)(lbase + 1 * LW + 4);
        float4 w2a = *(const float4*)(lbase + 2 * LW);
        float4 w2b = *(const float4*)(lbase + 2 * LW + 4);
        float4 w3a = *(const float4*)(lbase + 3 * LW);
        float4 w3b = *(const float4*)(lbase + 3 * LW + 4);
        float4 w4a = *(const float4*)(lbase + 4 * LW);
        float4 w4b = *(const float4*)(lbase + 4 * LW + 4);
        float4 w5a = *(const float4*)(lbase + 5 * LW);
        float4 w5b = *(const float4*)(lbase + 5 * LW + 4);

        float4 csA = add4(add4(add4(w0a, w1a), add4(w2a, w3a)), w4a);
        float4 csB = add4(add4(add4(w0b, w1b), add4(w2b, w3b)), w4b);

        const float4 p12a = max4(w1a, w2a), p12b = max4(w1b, w2b);
        const float4 p34a = max4(w3a, w4a), p34b = max4(w3b, w4b);
        const float4 cm0a = max34(w0a, p12a, p34a);
        const float4 cm0b = max34(w0b, p12b, p34b);

        float* __restrict__ orow =
            out + (size_t)plane * (HW * HW) + (size_t)(by0 + r0) * HW + (t * 64 + 4 * tx);

        proc_row(w0a,w0b, w1a,w1b, w2a,w2b, w3a,w3b, w4a,w4b,
                 cm0a, cm0b, csA, csB, bp, c04b, inv_bp, lam, orow);

        csA = add4(csA, sub4(w5a, w0a));
        csB = add4(csB, sub4(w5b, w0b));
        const float4 cm1a = max34(p12a, p34a, w5a);
        const float4 cm1b = max34(p12b, p34b, w5b);

        proc_row(w1a,w1b, w2a,w2b, w3a,w3b, w4a,w4b, w5a,w5b,
                 cm1a, cm1b, csA, csB, bp, c04b, inv_bp, lam, orow + HW);
    };

    float* out_ = out;  (void)out_;

    // ---- Software pipeline: stage(t+1) issues before compute(t); the
    // vmcnt drain sits in stage_write AFTER compute has covered the latency.
    Stage s0, s1, s2, s3;
    stage_load(0, s0);
    stage_write(0, s0);
    __builtin_amdgcn_wave_barrier();

    stage_load(1, s1);            // loads in flight during compute(0)
    compute(0, 0);
    stage_write(1, s1);
    __builtin_amdgcn_wave_barrier();

    stage_load(2, s2);
    compute(1, 1);
    stage_write(0, s2);           // note: buf index = (t+1)&1
    __builtin_amdgcn_wave_barrier();

    stage_load(3, s3);
    compute(2, 0);
    stage_write(1, s3);
    __builtin_amdgcn_wave_barrier();

    compute(3, 1);
}

extern "C" void kernel_launch(void* const* d_in, const int* in_sizes, int n_in,
                              void* d_out, int out_size, void* d_ws, size_t ws_size,
                              hipStream_t stream) {
    const float* x        = (const float*)d_in[0];
    const float* mix      = (const float*)d_in[1];
    const float* beta_raw = (const float*)d_in[2];
    float* out            = (float*)d_out;

    const int planes = in_sizes[0] / (HW * HW);     // B*C = 128
    const int C      = in_sizes[1];                 // 32
    // One 8x256 band per wave: planes * 32 bands / 4 waves per block.
    const int grid = planes * 8;                    // 1024 = 256 CUs x 4 blocks

    maxmedian_kernel<<<grid, 256, 0, stream>>>(x, mix, beta_raw, out, C);
}

// Round 16
// 36.761 us; speedup vs baseline: 1.0703x; 1.0233x over previous
//
#include <hip/hip_runtime.h>
#include <math.h>

#define HW 256
#define LW 68           // 2 halo + 64 + 2 halo
#define WLH 12          // per-wave tile rows: 8 output + 4 halo
#define NT 4            // horizontal tiles per band

typedef float f32x2 __attribute__((ext_vector_type(2)));

__device__ __forceinline__ int reflect_idx(int i) {
    i = (i < 0) ? -i : i;
    i = (i >= HW) ? (2 * HW - 2 - i) : i;
    return i;
}

__device__ __forceinline__ float4 max4(float4 a, float4 b) {
    float4 r; r.x = fmaxf(a.x, b.x); r.y = fmaxf(a.y, b.y);
    r.z = fmaxf(a.z, b.z); r.w = fmaxf(a.w, b.w); return r;
}
__device__ __forceinline__ float4 max34(float4 a, float4 b, float4 c) {
    float4 r; r.x = fmaxf(fmaxf(a.x, b.x), c.x); r.y = fmaxf(fmaxf(a.y, b.y), c.y);
    r.z = fmaxf(fmaxf(a.z, b.z), c.z); r.w = fmaxf(fmaxf(a.w, b.w), c.w); return r;
}
__device__ __forceinline__ float4 add4(float4 a, float4 b) {
    float4 r; r.x = a.x + b.x; r.y = a.y + b.y;
    r.z = a.z + b.z; r.w = a.w + b.w; return r;
}
__device__ __forceinline__ float4 sub4(float4 a, float4 b) {
    float4 r; r.x = a.x - b.x; r.y = a.y - b.y;
    r.z = a.z - b.z; r.w = a.w - b.w; return r;
}

struct Stage {          // one tile's staged data held in registers (13 VGPRs)
    float m[WLH];
    float h;
};

// One output row, 4 pixels, packed f32x2 tap loop with trans-pipe exp (R13).
__device__ __forceinline__ void proc_row(
    float4 A0, float4 B0, float4 A1, float4 B1, float4 A2, float4 B2,
    float4 A3, float4 B3, float4 A4, float4 B4,
    float4 cmA, float4 cmB, float4 csA, float4 csB,
    float bp, float c04b, float inv_bp, float lam,
    float* __restrict__ orow)
{
    const float cs[8] = {csA.x,csA.y,csA.z,csA.w, csB.x,csB.y,csB.z,csB.w};
    const float cm[8] = {cmA.x,cmA.y,cmA.z,cmA.w, cmB.x,cmB.y,cmB.z,cmB.w};
    const float vv[5][8] = {
        {A0.x,A0.y,A0.z,A0.w, B0.x,B0.y,B0.z,B0.w},
        {A1.x,A1.y,A1.z,A1.w, B1.x,B1.y,B1.z,B1.w},
        {A2.x,A2.y,A2.z,A2.w, B2.x,B2.y,B2.z,B2.w},
        {A3.x,A3.y,A3.z,A3.w, B3.x,B3.y,B3.z,B3.w},
        {A4.x,A4.y,A4.z,A4.w, B4.x,B4.y,B4.z,B4.w}};

    const float t12 = cs[1] + cs[2];
    const float t34 = cs[3] + cs[4];
    const float t56 = cs[5] + cs[6];
    const float u   = t12 + t34;
    const float w_  = t34 + t56;
    const float S[4] = {cs[0] + u, u + cs[5], cs[2] + w_, w_ + cs[7]};

    const float h12 = fmaxf(cm[1], cm[2]);
    const float h34 = fmaxf(cm[3], cm[4]);
    const float h56 = fmaxf(cm[5], cm[6]);
    const float m[4] = {fmaxf(fmaxf(cm[0], h12), h34),
                        fmaxf(fmaxf(h12, h34), cm[5]),
                        fmaxf(fmaxf(cm[2], h34), h56),
                        fmaxf(fmaxf(h34, h56), cm[7])};

    const f32x2 bp2   = {bp, bp};
    const f32x2 nbm01 = {-(S[0] * c04b), -(S[1] * c04b)};
    const f32x2 nbm23 = {-(S[2] * c04b), -(S[3] * c04b)};
    f32x2 ws01 = {0.0f, 0.0f}, ws23 = {0.0f, 0.0f};
    f32x2 wa01 = {0.0f, 0.0f}, wa23 = {0.0f, 0.0f};

    #pragma unroll
    for (int k = 0; k < 5; ++k) {
        #pragma unroll
        for (int j = 0; j < 5; ++j) {
            const f32x2 v01 = {vv[k][j],     vv[k][j + 1]};
            const f32x2 v23 = {vv[k][j + 2], vv[k][j + 3]};
            const f32x2 tv01 = __builtin_elementwise_fma(bp2, v01, nbm01);
            const f32x2 tv23 = __builtin_elementwise_fma(bp2, v23, nbm23);
            f32x2 e01, e23;
            e01.x = __builtin_amdgcn_exp2f(-fabsf(tv01.x));
            e01.y = __builtin_amdgcn_exp2f(-fabsf(tv01.y));
            e23.x = __builtin_amdgcn_exp2f(-fabsf(tv23.x));
            e23.y = __builtin_amdgcn_exp2f(-fabsf(tv23.y));
            ws01 += e01;
            ws23 += e23;
            wa01 = __builtin_elementwise_fma(e01, tv01, wa01);
            wa23 = __builtin_elementwise_fma(e23, tv23, wa23);
        }
    }

    const float ws[4] = {ws01.x, ws01.y, ws23.x, ws23.y};
    const float wa[4] = {wa01.x, wa01.y, wa23.x, wa23.y};

    float o[4];
    #pragma unroll
    for (int p = 0; p < 4; ++p) {
        const float mean = S[p] * 0.04f;
        const float med  = fmaf(wa[p] * __builtin_amdgcn_rcpf(ws[p]), inv_bp, mean);
        o[p] = fmaf(lam, med - m[p], m[p]);
    }
    float4 o4; o4.x = o[0]; o4.y = o[1]; o4.z = o[2]; o4.w = o[3];
    *(float4*)orow = o4;
}

__global__ __launch_bounds__(64)
void maxmedian_kernel(const float* __restrict__ x,
                      const float* __restrict__ mix,
                      const float* __restrict__ beta_raw,
                      float* __restrict__ out,
                      int C) {
    // One wave per block; double-buffered 12x68 tile (6.5 KB).
    __shared__ __align__(16) float lds[2][WLH * LW];

    const int lane = threadIdx.x;

    // Each block(=wave) owns one 8-row x 256-col band (4 tiles of 64 cols).
    const int band  = blockIdx.x;              // 0..4095
    const int plane = band >> 5;               // 32 bands per plane
    const int by0   = (band & 31) << 3;        // band's first output row

    const float* __restrict__ xp = x + (size_t)plane * (HW * HW);

    // Row addresses (vertical reflect), constant across the band's tiles.
    int gy[WLH];
    #pragma unroll
    for (int k = 0; k < WLH; ++k) gy[k] = reflect_idx(by0 - 2 + k) * HW;

    // Halo-lane mapping (lanes 0..47): 4 cols x 12 rows.
    const int hj   = lane & 3;
    const int hcol = (hj < 2) ? hj : (64 + hj);        // LDS col 0,1,66,67
    const int hoff = hcol - 2;                         // -2,-1,64,65
    const int gyh  = reflect_idx(by0 - 2 + (lane >> 2)) * HW;

    // ---- Parameters ----
    const int ch = plane % C;
    const float lam  = 1.0f / (1.0f + __expf(-mix[ch]));
    const float beta = 5.0f + 45.0f / (1.0f + __expf(-beta_raw[0]));
    const float bp     = beta * 1.44269504088896f;
    const float inv_bp = 1.0f / bp;
    const float c04b   = 0.04f * bp;

    // Compute-lane mapping: 4 cols x 2 rows per lane.
    const int tx = lane & 15;
    const int r0 = (lane >> 4) * 2;

    auto stage_load = [&](int t, Stage& s) {
        const int c0 = t * 64;
        #pragma unroll
        for (int k = 0; k < WLH; ++k)
            s.m[k] = xp[gy[k] + c0 + lane];
        if (lane < 48)
            s.h = xp[gyh + reflect_idx(c0 + hoff)];
    };
    auto stage_write = [&](int buf, const Stage& s) {
        float* __restrict__ b = lds[buf];
        #pragma unroll
        for (int k = 0; k < WLH; ++k)
            b[k * LW + 2 + lane] = s.m[k];
        if (lane < 48)
            b[(lane >> 2) * LW + hcol] = s.h;
    };
    auto compute = [&](int t, int buf) {
        const float* lbase = &lds[buf][r0 * LW + 4 * tx];

        float4 w0a = *(const float4*)(lbase + 0 * LW);
        float4 w0b = *(const float4*)(lbase + 0 * LW + 4);
        float4 w1a = *(const float4*)(lbase + 1 * LW);
        float4 w1b = *(const float4*)(lbase + 1 * LW + 4);
        float4 w2a = *(const float4*)(lbase + 2 * LW);
        float4 w2b = *(const float4*)(lbase + 2 * LW + 4);
        float4 w3a = *(const float4*)(lbase + 3 * LW);
        float4 w3b = *(const float4*)(lbase + 3 * LW + 4);
        float4 w4a = *(const float4*)(lbase + 4 * LW);
        float4 w4b = *(const float4*)(lbase + 4 * LW + 4);
        float4 w5a = *(const float4*)(lbase + 5 * LW);
        float4 w5b = *(const float4*)(lbase + 5 * LW + 4);

        float4 csA = add4(add4(add4(w0a, w1a), add4(w2a, w3a)), w4a);
        float4 csB = add4(add4(add4(w0b, w1b), add4(w2b, w3b)), w4b);

        const float4 p12a = max4(w1a, w2a), p12b = max4(w1b, w2b);
        const float4 p34a = max4(w3a, w4a), p34b = max4(w3b, w4b);
        const float4 cm0a = max34(w0a, p12a, p34a);
        const float4 cm0b = max34(w0b, p12b, p34b);

        float* __restrict__ orow =
            out + (size_t)plane * (HW * HW) + (size_t)(by0 + r0) * HW + (t * 64 + 4 * tx);

        proc_row(w0a,w0b, w1a,w1b, w2a,w2b, w3a,w3b, w4a,w4b,
                 cm0a, cm0b, csA, csB, bp, c04b, inv_bp, lam, orow);

        csA = add4(csA, sub4(w5a, w0a));
        csB = add4(csB, sub4(w5b, w0b));
        const float4 cm1a = max34(p12a, p34a, w5a);
        const float4 cm1b = max34(p12b, p34b, w5b);

        proc_row(w1a,w1b, w2a,w2b, w3a,w3b, w4a,w4b, w5a,w5b,
                 cm1a, cm1b, csA, csB, bp, c04b, inv_bp, lam, orow + HW);
    };

    // ---- Software pipeline: stage(t+1) loads in flight under compute(t).
    Stage s0, s1, s2, s3;
    stage_load(0, s0);
    stage_write(0, s0);
    __builtin_amdgcn_wave_barrier();

    stage_load(1, s1);
    compute(0, 0);
    stage_write(1, s1);
    __builtin_amdgcn_wave_barrier();

    stage_load(2, s2);
    compute(1, 1);
    stage_write(0, s2);
    __builtin_amdgcn_wave_barrier();

    stage_load(3, s3);
    compute(2, 0);
    stage_write(1, s3);
    __builtin_amdgcn_wave_barrier();

    compute(3, 1);
}

extern "C" void kernel_launch(void* const* d_in, const int* in_sizes, int n_in,
                              void* d_out, int out_size, void* d_ws, size_t ws_size,
                              hipStream_t stream) {
    const float* x        = (const float*)d_in[0];
    const float* mix      = (const float*)d_in[1];
    const float* beta_raw = (const float*)d_in[2];
    float* out            = (float*)d_out;

    const int planes = in_sizes[0] / (HW * HW);     // B*C = 128
    const int C      = in_sizes[1];                 // 32
    const int grid = planes * 32;                   // 4096 bands, 1 wave each

    maxmedian_kernel<<<grid, 64, 0, stream>>>(x, mix, beta_raw, out, C);
}